// Round 3
// baseline (286.260 us; speedup 1.0000x reference)
//
#include <hip/hip_runtime.h>
#include <hip/hip_bf16.h>
#include <math.h>

#define D_DIM 128
#define FF_DIM 512

typedef __attribute__((ext_vector_type(8))) short bf16x8;
typedef __attribute__((ext_vector_type(4))) float f32x4;
typedef __attribute__((ext_vector_type(4))) unsigned short u16x4;

__device__ __forceinline__ short f2bf(float f) {
    union { float f; unsigned u; } x; x.f = f;
    unsigned r = x.u + 0x7FFF + ((x.u >> 16) & 1);
    return (short)(r >> 16);
}
__device__ __forceinline__ float bf2f(short s) {
    union { unsigned u; float f; } x;
    x.u = ((unsigned)(unsigned short)s) << 16;
    return x.f;
}

__device__ __forceinline__ void load_lds16(const short* g, short* l) {
    __builtin_amdgcn_global_load_lds(
        (const __attribute__((address_space(1))) unsigned int*)g,
        (__attribute__((address_space(3))) unsigned int*)l, 16, 0, 0);
}

// ---------------------------------------------------------------------------
// bf16 MFMA GEMM: C[MP,Nc] = A[MP,K] @ W[Nc,K]^T + bias (+relu) (f32 or bf16 C)
// 128x128 tile, BK=32, 256 threads (4 waves, 2x2), 4x4 16x16 frags per wave.
// ---------------------------------------------------------------------------
template<int OUT_BF16, int RELU>
__global__ __launch_bounds__(256) void gemm_mfma(
    const short* __restrict__ A, const short* __restrict__ B,
    const float* __restrict__ bias, void* __restrict__ C,
    int Nc, int K)
{
    __shared__ short lA[128 * 32];
    __shared__ short lB[128 * 32];

    const int tid  = threadIdx.x;
    const int lane = tid & 63;
    const int wave = tid >> 6;
    const int wr = wave >> 1, wc = wave & 1;
    const int row0 = blockIdx.y * 128;
    const int col0 = blockIdx.x * 128;
    const int fr = lane & 15;          // frag row (A) / col (B)
    const int fq = lane >> 4;          // k-quarter
    const int sw = (fr >> 1) & 3;      // read-side chunk swizzle
    const int rdoff = (fq ^ sw) * 8;   // element offset within the 32-k row

    f32x4 acc[4][4] = {};

    for (int k0 = 0; k0 < K; k0 += 32) {
        __syncthreads();
#pragma unroll
        for (int i = 0; i < 2; ++i) {
            int c  = i * 256 + tid;            // 16B chunk id 0..511
            int r  = c >> 2;                   // tile row 0..127
            int qs = c & 3;                    // LDS chunk slot in row
            int qg = qs ^ ((r >> 1) & 3);      // pre-swizzled global chunk
            load_lds16(A + (size_t)(row0 + r) * K + k0 + qg * 8, lA + c * 8);
            load_lds16(B + (size_t)(col0 + r) * K + k0 + qg * 8, lB + c * 8);
        }
        __syncthreads();

        bf16x8 af[4], bfr[4];
#pragma unroll
        for (int m = 0; m < 4; ++m)
            af[m] = *(const bf16x8*)&lA[(wr * 64 + m * 16 + fr) * 32 + rdoff];
#pragma unroll
        for (int n2 = 0; n2 < 4; ++n2)
            bfr[n2] = *(const bf16x8*)&lB[(wc * 64 + n2 * 16 + fr) * 32 + rdoff];
#pragma unroll
        for (int m = 0; m < 4; ++m)
#pragma unroll
            for (int n2 = 0; n2 < 4; ++n2)
                acc[m][n2] = __builtin_amdgcn_mfma_f32_16x16x32_bf16(
                    af[m], bfr[n2], acc[m][n2], 0, 0, 0);
    }

    // epilogue: C/D layout col=lane&15, row=(lane>>4)*4+j
#pragma unroll
    for (int m = 0; m < 4; ++m) {
        int r = row0 + wr * 64 + m * 16 + fq * 4;
#pragma unroll
        for (int n2 = 0; n2 < 4; ++n2) {
            int c = col0 + wc * 64 + n2 * 16 + fr;
            float bb = bias[c];
#pragma unroll
            for (int j = 0; j < 4; ++j) {
                float v = acc[m][n2][j] + bb;
                if (RELU) v = fmaxf(v, 0.0f);
                if (OUT_BF16)
                    ((short*)C)[(size_t)(r + j) * Nc + c] = f2bf(v);
                else
                    ((float*)C)[(size_t)(r + j) * Nc + c] = v;
            }
        }
    }
}

// ---------------------------------------------------------------------------
// node_states f32 -> bf16 (padded rows zeroed) + copy old states to d_out
// ---------------------------------------------------------------------------
__global__ __launch_bounds__(256) void conv_ns_kernel(
    const float* __restrict__ ns, short* __restrict__ nsbf,
    float* __restrict__ out_old, int n_elems, int mp_elems)
{
    int i4 = (blockIdx.x * 256 + threadIdx.x) * 4;
    if (i4 >= mp_elems) return;
    if (i4 < n_elems) {
        float4 v = *(const float4*)(ns + i4);
        *(float4*)(out_old + i4) = v;
        u16x4 b;
        b.x = (unsigned short)f2bf(v.x); b.y = (unsigned short)f2bf(v.y);
        b.z = (unsigned short)f2bf(v.z); b.w = (unsigned short)f2bf(v.w);
        *(u16x4*)(nsbf + i4) = b;
    } else {
        u16x4 z = {0, 0, 0, 0};
        *(u16x4*)(nsbf + i4) = z;
    }
}

// all four weight matrices f32 -> bf16 in one launch
__global__ __launch_bounds__(256) void conv_w_kernel(
    const float* w0, const float* w1, const float* w2, const float* w3,
    short* o0, short* o1, short* o2, short* o3,
    int c0, int c1, int c2, int c3)
{
    int i = blockIdx.x * 256 + threadIdx.x;
    if (i < c0) o0[i] = f2bf(w0[i]);
    if (i < c1) o1[i] = f2bf(w1[i]);
    if (i < c2) o2[i] = f2bf(w2[i]);
    if (i < c3) o3[i] = f2bf(w3[i]);
}

// ---------------------------------------------------------------------------
// CSR build: count -> hierarchical scan -> scatter
// ---------------------------------------------------------------------------
__global__ __launch_bounds__(256) void count_kernel(
    const int* __restrict__ tgt, int* __restrict__ counts, int m)
{
    int i = blockIdx.x * blockDim.x + threadIdx.x;
    if (i < m) atomicAdd(&counts[tgt[i]], 1);
}

__global__ __launch_bounds__(256) void scan1_kernel(
    const int* __restrict__ counts, int* __restrict__ offs,
    int* __restrict__ bsum, int n)
{
    __shared__ int sd[256];
    int t = threadIdx.x;
    int i = blockIdx.x * 256 + t;
    int v = (i < n) ? counts[i] : 0;
    sd[t] = v;
    __syncthreads();
    for (int o = 1; o < 256; o <<= 1) {
        int x = (t >= o) ? sd[t - o] : 0;
        __syncthreads();
        sd[t] += x;
        __syncthreads();
    }
    if (i < n) offs[i] = sd[t] - v;
    if (t == 255) bsum[blockIdx.x] = sd[255];
}

__global__ __launch_bounds__(256) void scan2_kernel(
    int* __restrict__ bsum, int nb)
{
    __shared__ int sd[256];
    int t = threadIdx.x;
    int v = (t < nb) ? bsum[t] : 0;
    sd[t] = v;
    __syncthreads();
    for (int o = 1; o < 256; o <<= 1) {
        int x = (t >= o) ? sd[t - o] : 0;
        __syncthreads();
        sd[t] += x;
        __syncthreads();
    }
    if (t < nb) bsum[t] = sd[t] - v;   // exclusive
}

__global__ __launch_bounds__(256) void scan3_kernel(
    int* __restrict__ offs, const int* __restrict__ bsum,
    int* __restrict__ cursor, int n, int m)
{
    int i = blockIdx.x * 256 + threadIdx.x;
    if (i < n) {
        int v = offs[i] + bsum[blockIdx.x];
        offs[i] = v;
        cursor[i] = v;
    }
    if (i == 0) offs[n] = m;
}

__global__ __launch_bounds__(256) void scatter_kernel(
    const int* __restrict__ src, const int* __restrict__ tgt,
    int* __restrict__ cursor, int* __restrict__ csr_src, int m)
{
    int i = blockIdx.x * blockDim.x + threadIdx.x;
    if (i < m) {
        int pos = atomicAdd(&cursor[tgt[i]], 1);
        csr_src[pos] = src[i];
    }
}

// ---------------------------------------------------------------------------
// Per-target-node attention: blocked two-phase softmax, register-held V.
// One wave per node; lane covers dims {2l,2l+1}; 8-lane groups = heads.
// Chunk of 32 edges: phase 1 issues all K/V gathers (high MLP) + scores;
// phase 2 does tree-max, independent exps, partial-sum accumulate; single
// online-softmax rescale per chunk (exact for any degree).
// ---------------------------------------------------------------------------
__global__ __launch_bounds__(256) void attn_kernel(
    const short* __restrict__ qkv, const int* __restrict__ offsets,
    const int* __restrict__ csr_src, short* __restrict__ agg, int n, int mp)
{
    int node = blockIdx.x * 4 + (threadIdx.x >> 6);
    int lane = threadIdx.x & 63;
    if (node >= mp) return;
    const int d0 = lane * 2;
    unsigned* outp = (unsigned*)(agg + (size_t)node * 128 + d0);
    if (node >= n) { *outp = 0u; return; }

    unsigned qw = *(const unsigned*)(qkv + (size_t)node * 384 + d0);
    float q0 = bf2f((short)(qw & 0xFFFF));
    float q1 = bf2f((short)(qw >> 16));

    int beg = offsets[node];
    int end = offsets[node + 1];

    float m = -INFINITY, l = 0.0f, acc0 = 0.0f, acc1 = 0.0f;

    for (int c0 = beg; c0 < end; c0 += 32) {
        int cnt = end - c0; if (cnt > 32) cnt = 32;
        int mysrc = (lane < cnt) ? csr_src[c0 + lane] : 0;

        float s[32];
        unsigned vw[32];
#pragma unroll
        for (int i = 0; i < 32; ++i) {
            if (i < cnt) {
                int src = __shfl(mysrc, i);
                const short* row = qkv + (size_t)src * 384;
                unsigned kw = *(const unsigned*)(row + 128 + d0);
                vw[i] = *(const unsigned*)(row + 256 + d0);
                float part = q0 * bf2f((short)(kw & 0xFFFF))
                           + q1 * bf2f((short)(kw >> 16));
                part += __shfl_xor(part, 1);
                part += __shfl_xor(part, 2);
                part += __shfl_xor(part, 4);
                s[i] = part * 0.25f;
            } else {
                s[i] = -INFINITY;
                vw[i] = 0u;
            }
        }

        // chunk max: 4 partial chains + combine
        float mx0 = s[0], mx1 = s[1], mx2 = s[2], mx3 = s[3];
#pragma unroll
        for (int i = 4; i < 32; i += 4) {
            mx0 = fmaxf(mx0, s[i]);     mx1 = fmaxf(mx1, s[i + 1]);
            mx2 = fmaxf(mx2, s[i + 2]); mx3 = fmaxf(mx3, s[i + 3]);
        }
        float mnew = fmaxf(fmaxf(fmaxf(mx0, mx1), fmaxf(mx2, mx3)), m);
        float corr = __expf(m - mnew);    // first chunk: exp(-inf)=0

        float l0 = 0, l1 = 0, t0 = 0, t1 = 0, u0 = 0, u1 = 0;
#pragma unroll
        for (int i = 0; i < 32; i += 2) {
            float pa = __expf(s[i] - mnew);
            float pb = __expf(s[i + 1] - mnew);
            l0 += pa; l1 += pb;
            t0 += pa * bf2f((short)(vw[i] & 0xFFFF));
            u0 += pa * bf2f((short)(vw[i] >> 16));
            t1 += pb * bf2f((short)(vw[i + 1] & 0xFFFF));
            u1 += pb * bf2f((short)(vw[i + 1] >> 16));
        }
        l    = l    * corr + l0 + l1;
        acc0 = acc0 * corr + t0 + t1;
        acc1 = acc1 * corr + u0 + u1;
        m = mnew;
    }

    float inv = (l > 0.0f) ? 1.0f / l : 0.0f;
    *outp = ((unsigned)(unsigned short)f2bf(acc1 * inv) << 16) |
            (unsigned)(unsigned short)f2bf(acc0 * inv);
}

// ---------------------------------------------------------------------------
// LN1: x = LN(ns + msg); writes x f32 (rows<n) and x bf16 (pad rows zeroed)
// ---------------------------------------------------------------------------
__global__ __launch_bounds__(256) void ln1_kernel(
    const float* __restrict__ ns, const float* __restrict__ msg,
    const float* __restrict__ g, const float* __restrict__ b,
    float* __restrict__ x32, short* __restrict__ xbf, int n, int mp)
{
    int row = blockIdx.x * 4 + (threadIdx.x >> 6);
    int lane = threadIdx.x & 63;
    if (row >= mp) return;
    const int d0 = lane * 2;
    size_t base = (size_t)row * 128 + d0;

    if (row >= n) {
        *(unsigned*)(xbf + base) = 0u;
        return;
    }

    float v0 = ns[base] + msg[base];
    float v1 = ns[base + 1] + msg[base + 1];

    float s = v0 + v1;
#pragma unroll
    for (int off = 1; off < 64; off <<= 1) s += __shfl_xor(s, off);
    float mu = s * (1.0f / 128.0f);

    float dv0 = v0 - mu, dv1 = v1 - mu;
    float ss = dv0 * dv0 + dv1 * dv1;
#pragma unroll
    for (int off = 1; off < 64; off <<= 1) ss += __shfl_xor(ss, off);
    float rstd = rsqrtf(ss * (1.0f / 128.0f) + 1e-5f);

    float o0 = g[d0] * dv0 * rstd + b[d0];
    float o1 = g[d0 + 1] * dv1 * rstd + b[d0 + 1];
    x32[base] = o0;
    x32[base + 1] = o1;
    unsigned ob = ((unsigned)(unsigned short)f2bf(o1) << 16) |
                  (unsigned)(unsigned short)f2bf(o0);
    *(unsigned*)(xbf + base) = ob;
}

// LN2: out = LN(x + ff2), f32 out, rows < n
__global__ __launch_bounds__(256) void ln2_kernel(
    const float* __restrict__ x, const float* __restrict__ y,
    const float* __restrict__ g, const float* __restrict__ b,
    float* __restrict__ out, int n)
{
    int row = blockIdx.x * 4 + (threadIdx.x >> 6);
    int lane = threadIdx.x & 63;
    if (row >= n) return;
    const int d0 = lane * 2;
    size_t base = (size_t)row * 128 + d0;
    float v0 = x[base] + y[base];
    float v1 = x[base + 1] + y[base + 1];

    float s = v0 + v1;
#pragma unroll
    for (int off = 1; off < 64; off <<= 1) s += __shfl_xor(s, off);
    float mu = s * (1.0f / 128.0f);

    float dv0 = v0 - mu, dv1 = v1 - mu;
    float ss = dv0 * dv0 + dv1 * dv1;
#pragma unroll
    for (int off = 1; off < 64; off <<= 1) ss += __shfl_xor(ss, off);
    float rstd = rsqrtf(ss * (1.0f / 128.0f) + 1e-5f);

    out[base]     = g[d0] * dv0 * rstd + b[d0];
    out[base + 1] = g[d0 + 1] * dv1 * rstd + b[d0 + 1];
}

// ---------------------------------------------------------------------------
extern "C" void kernel_launch(void* const* d_in, const int* in_sizes, int n_in,
                              void* d_out, int out_size, void* d_ws, size_t ws_size,
                              hipStream_t stream)
{
    const float* node_states = (const float*)d_in[0];
    const int*   edges       = (const int*)d_in[1];
    const float* w_qkv = (const float*)d_in[2];
    const float* b_qkv = (const float*)d_in[3];
    const float* w_out = (const float*)d_in[4];
    const float* b_out = (const float*)d_in[5];
    const float* w1    = (const float*)d_in[6];
    const float* b1    = (const float*)d_in[7];
    const float* w2    = (const float*)d_in[8];
    const float* b2    = (const float*)d_in[9];
    const float* g1    = (const float*)d_in[10];
    const float* beta1 = (const float*)d_in[11];
    const float* g2    = (const float*)d_in[12];
    const float* beta2 = (const float*)d_in[13];

    const int N  = in_sizes[0] / D_DIM;      // 40000
    const int M  = in_sizes[1] / 2;          // 640000
    const int MP = ((N + 127) / 128) * 128;  // 40064
    const int* e_src = edges;
    const int* e_tgt = edges + M;

    float* out_new = (float*)d_out;
    float* out_old = (float*)d_out + (size_t)N * D_DIM;

    size_t off = 0;
    auto alloc = [&](size_t bytes) -> void* {
        void* p = (char*)d_ws + off;
        off += (bytes + 255) & ~(size_t)255;
        return p;
    };
    short* ns_bf   = (short*)alloc((size_t)MP * D_DIM * 2);
    // region: qkv_bf [MP][384] early; xbuf f32 [MP][128] + xbuf_bf [MP][128] later
    char*  region  = (char*)alloc((size_t)MP * 384 * 2);
    short* qkv_bf  = (short*)region;
    float* xbuf    = (float*)region;
    short* xbuf_bf = (short*)(region + (size_t)MP * D_DIM * 4);
    short* agg_bf  = (short*)alloc((size_t)MP * D_DIM * 2);
    float* msg     = (float*)alloc((size_t)MP * D_DIM * 4);     // also ff2 out
    short* ff1_bf  = (short*)alloc((size_t)MP * FF_DIM * 2);
    short* wqkv_bf = (short*)alloc((size_t)384 * 128 * 2);
    short* wout_bf = (short*)alloc((size_t)128 * 128 * 2);
    short* w1_bf   = (short*)alloc((size_t)512 * 128 * 2);
    short* w2_bf   = (short*)alloc((size_t)128 * 512 * 2);
    int* counts    = (int*)alloc((size_t)N * 4);
    int* offsets   = (int*)alloc((size_t)(N + 1) * 4);
    int* cursor    = (int*)alloc((size_t)N * 4);
    int* bsum      = (int*)alloc((size_t)256 * 4);
    int* csr_src   = (int*)alloc((size_t)M * 4);
    (void)ws_size;

    const int nb = (N + 255) / 256;   // 157 scan blocks

    // conversions (+ old-state copy fused)
    conv_ns_kernel<<<(MP * D_DIM / 4 + 255) / 256, 256, 0, stream>>>(
        node_states, ns_bf, out_old, N * D_DIM, MP * D_DIM);
    conv_w_kernel<<<(512 * 128 + 255) / 256, 256, 0, stream>>>(
        w_qkv, w_out, w1, w2, wqkv_bf, wout_bf, w1_bf, w2_bf,
        384 * 128, 128 * 128, 512 * 128, 128 * 512);

    // CSR build
    hipMemsetAsync(counts, 0, (size_t)N * 4, stream);
    count_kernel<<<(M + 255) / 256, 256, 0, stream>>>(e_tgt, counts, M);
    scan1_kernel<<<nb, 256, 0, stream>>>(counts, offsets, bsum, N);
    scan2_kernel<<<1, 256, 0, stream>>>(bsum, nb);
    scan3_kernel<<<nb, 256, 0, stream>>>(offsets, bsum, cursor, N, M);
    scatter_kernel<<<(M + 255) / 256, 256, 0, stream>>>(e_src, e_tgt, cursor,
                                                        csr_src, M);

    // 1) qkv = ns @ w_qkv^T + b_qkv  (bf16 out)
    {
        dim3 grid(384 / 128, MP / 128);
        gemm_mfma<1, 0><<<grid, 256, 0, stream>>>(ns_bf, wqkv_bf, b_qkv,
                                                  qkv_bf, 384, 128);
    }
    // 2) attention aggregation
    attn_kernel<<<MP / 4, 256, 0, stream>>>(qkv_bf, offsets, csr_src,
                                            agg_bf, N, MP);
    // 3) msg = agg @ w_out^T + b_out  (f32 out)
    {
        dim3 grid(1, MP / 128);
        gemm_mfma<0, 0><<<grid, 256, 0, stream>>>(agg_bf, wout_bf, b_out,
                                                  msg, 128, 128);
    }
    // 4) x = LN(ns + msg)  -> xbuf f32 + xbuf_bf   (overwrites dead qkv_bf)
    ln1_kernel<<<MP / 4, 256, 0, stream>>>(node_states, msg, g1, beta1,
                                           xbuf, xbuf_bf, N, MP);
    // 5) ff1 = relu(x @ w1^T + b1)  (bf16 out)
    {
        dim3 grid(FF_DIM / 128, MP / 128);
        gemm_mfma<1, 1><<<grid, 256, 0, stream>>>(xbuf_bf, w1_bf, b1,
                                                  ff1_bf, FF_DIM, 128);
    }
    // 6) ff2 = ff1 @ w2^T + b2  (f32 out, reuse msg)
    {
        dim3 grid(1, MP / 128);
        gemm_mfma<0, 0><<<grid, 256, 0, stream>>>(ff1_bf, w2_bf, b2,
                                                  msg, 128, 512);
    }
    // 7) out = LN(x + ff2)
    ln2_kernel<<<(N + 3) / 4, 256, 0, stream>>>(xbuf, msg, g2, beta2,
                                                out_new, N);
}

// Round 4
// 219.804 us; speedup vs baseline: 1.3023x; 1.3023x over previous
//
#include <hip/hip_runtime.h>
#include <hip/hip_bf16.h>
#include <math.h>

#define D_DIM 128
#define FF_DIM 512

typedef __attribute__((ext_vector_type(8))) short bf16x8;
typedef __attribute__((ext_vector_type(4))) float f32x4;
typedef __attribute__((ext_vector_type(4))) unsigned short u16x4;
typedef __attribute__((ext_vector_type(2))) unsigned u32x2;

__device__ __forceinline__ short f2bf(float f) {
    union { float f; unsigned u; } x; x.f = f;
    unsigned r = x.u + 0x7FFF + ((x.u >> 16) & 1);
    return (short)(r >> 16);
}
__device__ __forceinline__ float bf2f(short s) {
    union { unsigned u; float f; } x;
    x.u = ((unsigned)(unsigned short)s) << 16;
    return x.f;
}

__device__ __forceinline__ void load_lds16(const short* g, short* l) {
    __builtin_amdgcn_global_load_lds(
        (const __attribute__((address_space(1))) unsigned int*)g,
        (__attribute__((address_space(3))) unsigned int*)l, 16, 0, 0);
}

// ---------------------------------------------------------------------------
// bf16 MFMA GEMM: C[MP,Nc] = A[MP,K] @ W[Nc,K]^T + bias (+relu) (f32/bf16 C)
// 128x128 tile, BK=32, 256 threads (4 waves, 2x2), 4x4 16x16 frags per wave.
// KVPACK: remap output cols so K/V dims interleave as {k0,k1,v0,v1} per pair
// (for the attention gather: one 8B load per edge per lane).
// ---------------------------------------------------------------------------
template<int OUT_BF16, int RELU, int KVPACK>
__global__ __launch_bounds__(256) void gemm_mfma(
    const short* __restrict__ A, const short* __restrict__ B,
    const float* __restrict__ bias, void* __restrict__ C,
    int Nc, int K)
{
    __shared__ short lA[128 * 32];
    __shared__ short lB[128 * 32];

    const int tid  = threadIdx.x;
    const int lane = tid & 63;
    const int wave = tid >> 6;
    const int wr = wave >> 1, wc = wave & 1;
    const int row0 = blockIdx.y * 128;
    const int col0 = blockIdx.x * 128;
    const int fr = lane & 15;          // frag row (A) / col (B)
    const int fq = lane >> 4;          // k-quarter
    const int sw = (fr >> 1) & 3;      // read-side chunk swizzle
    const int rdoff = (fq ^ sw) * 8;   // element offset within the 32-k row

    f32x4 acc[4][4] = {};

    for (int k0 = 0; k0 < K; k0 += 32) {
        __syncthreads();
#pragma unroll
        for (int i = 0; i < 2; ++i) {
            int c  = i * 256 + tid;            // 16B chunk id 0..511
            int r  = c >> 2;                   // tile row 0..127
            int qs = c & 3;                    // LDS chunk slot in row
            int qg = qs ^ ((r >> 1) & 3);      // pre-swizzled global chunk
            load_lds16(A + (size_t)(row0 + r) * K + k0 + qg * 8, lA + c * 8);
            load_lds16(B + (size_t)(col0 + r) * K + k0 + qg * 8, lB + c * 8);
        }
        __syncthreads();

        bf16x8 af[4], bfr[4];
#pragma unroll
        for (int m = 0; m < 4; ++m)
            af[m] = *(const bf16x8*)&lA[(wr * 64 + m * 16 + fr) * 32 + rdoff];
#pragma unroll
        for (int n2 = 0; n2 < 4; ++n2)
            bfr[n2] = *(const bf16x8*)&lB[(wc * 64 + n2 * 16 + fr) * 32 + rdoff];
#pragma unroll
        for (int m = 0; m < 4; ++m)
#pragma unroll
            for (int n2 = 0; n2 < 4; ++n2)
                acc[m][n2] = __builtin_amdgcn_mfma_f32_16x16x32_bf16(
                    af[m], bfr[n2], acc[m][n2], 0, 0, 0);
    }

    // epilogue: C/D layout col=lane&15, row=(lane>>4)*4+j
#pragma unroll
    for (int m = 0; m < 4; ++m) {
        int r = row0 + wr * 64 + m * 16 + fq * 4;
#pragma unroll
        for (int n2 = 0; n2 < 4; ++n2) {
            int c = col0 + wc * 64 + n2 * 16 + fr;
            float bb = bias[c];
            int cc = c;
            if (KVPACK) {
                // q: [0,128) unchanged; k dim d -> 128+4*(d>>1)+(d&1);
                // v dim d -> 128+4*(d>>1)+2+(d&1)   (block-uniform branch)
                if (c >= 256)      { int d = c - 256; cc = 128 + ((d >> 1) << 2) + 2 + (d & 1); }
                else if (c >= 128) { int d = c - 128; cc = 128 + ((d >> 1) << 2) + (d & 1); }
            }
#pragma unroll
            for (int j = 0; j < 4; ++j) {
                float v = acc[m][n2][j] + bb;
                if (RELU) v = fmaxf(v, 0.0f);
                if (OUT_BF16)
                    ((short*)C)[(size_t)(r + j) * Nc + cc] = f2bf(v);
                else
                    ((float*)C)[(size_t)(r + j) * Nc + cc] = v;
            }
        }
    }
}

// ---------------------------------------------------------------------------
// node_states f32 -> bf16 (padded rows zeroed) + copy old states to d_out
// ---------------------------------------------------------------------------
__global__ __launch_bounds__(256) void conv_ns_kernel(
    const float* __restrict__ ns, short* __restrict__ nsbf,
    float* __restrict__ out_old, int n_elems, int mp_elems)
{
    int i4 = (blockIdx.x * 256 + threadIdx.x) * 4;
    if (i4 >= mp_elems) return;
    if (i4 < n_elems) {
        float4 v = *(const float4*)(ns + i4);
        *(float4*)(out_old + i4) = v;
        u16x4 b;
        b.x = (unsigned short)f2bf(v.x); b.y = (unsigned short)f2bf(v.y);
        b.z = (unsigned short)f2bf(v.z); b.w = (unsigned short)f2bf(v.w);
        *(u16x4*)(nsbf + i4) = b;
    } else {
        u16x4 z = {0, 0, 0, 0};
        *(u16x4*)(nsbf + i4) = z;
    }
}

// all four weight matrices f32 -> bf16 in one launch
__global__ __launch_bounds__(256) void conv_w_kernel(
    const float* w0, const float* w1, const float* w2, const float* w3,
    short* o0, short* o1, short* o2, short* o3,
    int c0, int c1, int c2, int c3)
{
    int i = blockIdx.x * 256 + threadIdx.x;
    if (i < c0) o0[i] = f2bf(w0[i]);
    if (i < c1) o1[i] = f2bf(w1[i]);
    if (i < c2) o2[i] = f2bf(w2[i]);
    if (i < c3) o3[i] = f2bf(w3[i]);
}

// ---------------------------------------------------------------------------
// CSR build: count -> hierarchical scan -> scatter
// ---------------------------------------------------------------------------
__global__ __launch_bounds__(256) void count_kernel(
    const int* __restrict__ tgt, int* __restrict__ counts, int m)
{
    int i = blockIdx.x * blockDim.x + threadIdx.x;
    if (i < m) atomicAdd(&counts[tgt[i]], 1);
}

__global__ __launch_bounds__(256) void scan1_kernel(
    const int* __restrict__ counts, int* __restrict__ offs,
    int* __restrict__ bsum, int n)
{
    __shared__ int sd[256];
    int t = threadIdx.x;
    int i = blockIdx.x * 256 + t;
    int v = (i < n) ? counts[i] : 0;
    sd[t] = v;
    __syncthreads();
    for (int o = 1; o < 256; o <<= 1) {
        int x = (t >= o) ? sd[t - o] : 0;
        __syncthreads();
        sd[t] += x;
        __syncthreads();
    }
    if (i < n) offs[i] = sd[t] - v;
    if (t == 255) bsum[blockIdx.x] = sd[255];
}

__global__ __launch_bounds__(256) void scan2_kernel(
    int* __restrict__ bsum, int nb)
{
    __shared__ int sd[256];
    int t = threadIdx.x;
    int v = (t < nb) ? bsum[t] : 0;
    sd[t] = v;
    __syncthreads();
    for (int o = 1; o < 256; o <<= 1) {
        int x = (t >= o) ? sd[t - o] : 0;
        __syncthreads();
        sd[t] += x;
        __syncthreads();
    }
    if (t < nb) bsum[t] = sd[t] - v;   // exclusive
}

__global__ __launch_bounds__(256) void scan3_kernel(
    int* __restrict__ offs, const int* __restrict__ bsum,
    int* __restrict__ cursor, int n, int m)
{
    int i = blockIdx.x * 256 + threadIdx.x;
    if (i < n) {
        int v = offs[i] + bsum[blockIdx.x];
        offs[i] = v;
        cursor[i] = v;
    }
    if (i == 0) offs[n] = m;
}

__global__ __launch_bounds__(256) void scatter_kernel(
    const int* __restrict__ src, const int* __restrict__ tgt,
    int* __restrict__ cursor, int* __restrict__ csr_src, int m)
{
    int i = blockIdx.x * blockDim.x + threadIdx.x;
    if (i < m) {
        int pos = atomicAdd(&cursor[tgt[i]], 1);
        csr_src[pos] = src[i];
    }
}

// ---------------------------------------------------------------------------
// Per-target-node attention: depth-4 rotating software pipeline.
// One wave per node; lane covers dims {2l,2l+1}; 8-lane groups = heads.
// qkv layout: q[128] | kv-interleaved {k0,k1,v0,v1}*64  (KVPACK) per row.
// One 8B gather per edge per lane; 4 in flight; online softmax per edge.
// ---------------------------------------------------------------------------
__global__ __launch_bounds__(256) void attn_kernel(
    const short* __restrict__ qkv, const int* __restrict__ offsets,
    const int* __restrict__ csr_src, short* __restrict__ agg, int n, int mp)
{
    int node = blockIdx.x * 4 + (threadIdx.x >> 6);
    int lane = threadIdx.x & 63;
    if (node >= mp) return;
    const int d0 = lane * 2;
    unsigned* outp = (unsigned*)(agg + (size_t)node * 128 + d0);
    if (node >= n) { *outp = 0u; return; }

    unsigned qw = *(const unsigned*)(qkv + (size_t)node * 384 + d0);
    float q0 = bf2f((short)(qw & 0xFFFF));
    float q1 = bf2f((short)(qw >> 16));

    int beg = offsets[node];
    int end = offsets[node + 1];

    float m = -INFINITY, l = 0.0f, acc0 = 0.0f, acc1 = 0.0f;
    const int kvoff = 128 + 4 * lane;   // shorts: {k0,k1,v0,v1} for this lane

#define LOADKV(dst, IDX) { int s_ = __shfl(mysrc, (IDX) & 63); \
    dst = *(const u32x2*)(qkv + (size_t)s_ * 384 + kvoff); }

    for (int c0 = beg; c0 < end; c0 += 64) {
        int cnt = end - c0; if (cnt > 64) cnt = 64;
        int mysrc = (lane < cnt) ? csr_src[c0 + lane] : 0;

        u32x2 kv0, kv1, kv2, kv3;
        LOADKV(kv0, 0) LOADKV(kv1, 1) LOADKV(kv2, 2) LOADKV(kv3, 3)

        for (int g = 0; g < cnt; g += 4) {
#define STEPJ(J, KV) { \
            u32x2 cur = KV; \
            LOADKV(KV, g + 4 + J) \
            float part = q0 * bf2f((short)(cur.x & 0xFFFF)) \
                       + q1 * bf2f((short)(cur.x >> 16)); \
            part += __shfl_xor(part, 1); \
            part += __shfl_xor(part, 2); \
            part += __shfl_xor(part, 4); \
            float sc = (g + J < cnt) ? part * 0.25f : -INFINITY; \
            float mnew = fmaxf(m, sc); \
            float corr = __expf(m - mnew); \
            float p = __expf(sc - mnew); \
            l = l * corr + p; \
            acc0 = acc0 * corr + p * bf2f((short)(cur.y & 0xFFFF)); \
            acc1 = acc1 * corr + p * bf2f((short)(cur.y >> 16)); \
            m = mnew; }
            STEPJ(0, kv0) STEPJ(1, kv1) STEPJ(2, kv2) STEPJ(3, kv3)
#undef STEPJ
        }
    }
#undef LOADKV

    float inv = (l > 0.0f) ? 1.0f / l : 0.0f;
    *outp = ((unsigned)(unsigned short)f2bf(acc1 * inv) << 16) |
            (unsigned)(unsigned short)f2bf(acc0 * inv);
}

// ---------------------------------------------------------------------------
// LN1: x = LN(ns + msg); writes x f32 (rows<n) and x bf16 (pad rows zeroed)
// ---------------------------------------------------------------------------
__global__ __launch_bounds__(256) void ln1_kernel(
    const float* __restrict__ ns, const float* __restrict__ msg,
    const float* __restrict__ g, const float* __restrict__ b,
    float* __restrict__ x32, short* __restrict__ xbf, int n, int mp)
{
    int row = blockIdx.x * 4 + (threadIdx.x >> 6);
    int lane = threadIdx.x & 63;
    if (row >= mp) return;
    const int d0 = lane * 2;
    size_t base = (size_t)row * 128 + d0;

    if (row >= n) {
        *(unsigned*)(xbf + base) = 0u;
        return;
    }

    float v0 = ns[base] + msg[base];
    float v1 = ns[base + 1] + msg[base + 1];

    float s = v0 + v1;
#pragma unroll
    for (int off = 1; off < 64; off <<= 1) s += __shfl_xor(s, off);
    float mu = s * (1.0f / 128.0f);

    float dv0 = v0 - mu, dv1 = v1 - mu;
    float ss = dv0 * dv0 + dv1 * dv1;
#pragma unroll
    for (int off = 1; off < 64; off <<= 1) ss += __shfl_xor(ss, off);
    float rstd = rsqrtf(ss * (1.0f / 128.0f) + 1e-5f);

    float o0 = g[d0] * dv0 * rstd + b[d0];
    float o1 = g[d0 + 1] * dv1 * rstd + b[d0 + 1];
    x32[base] = o0;
    x32[base + 1] = o1;
    unsigned ob = ((unsigned)(unsigned short)f2bf(o1) << 16) |
                  (unsigned)(unsigned short)f2bf(o0);
    *(unsigned*)(xbf + base) = ob;
}

// LN2: out = LN(x + ff2), f32 out, rows < n
__global__ __launch_bounds__(256) void ln2_kernel(
    const float* __restrict__ x, const float* __restrict__ y,
    const float* __restrict__ g, const float* __restrict__ b,
    float* __restrict__ out, int n)
{
    int row = blockIdx.x * 4 + (threadIdx.x >> 6);
    int lane = threadIdx.x & 63;
    if (row >= n) return;
    const int d0 = lane * 2;
    size_t base = (size_t)row * 128 + d0;
    float v0 = x[base] + y[base];
    float v1 = x[base + 1] + y[base + 1];

    float s = v0 + v1;
#pragma unroll
    for (int off = 1; off < 64; off <<= 1) s += __shfl_xor(s, off);
    float mu = s * (1.0f / 128.0f);

    float dv0 = v0 - mu, dv1 = v1 - mu;
    float ss = dv0 * dv0 + dv1 * dv1;
#pragma unroll
    for (int off = 1; off < 64; off <<= 1) ss += __shfl_xor(ss, off);
    float rstd = rsqrtf(ss * (1.0f / 128.0f) + 1e-5f);

    out[base]     = g[d0] * dv0 * rstd + b[d0];
    out[base + 1] = g[d0 + 1] * dv1 * rstd + b[d0 + 1];
}

// ---------------------------------------------------------------------------
extern "C" void kernel_launch(void* const* d_in, const int* in_sizes, int n_in,
                              void* d_out, int out_size, void* d_ws, size_t ws_size,
                              hipStream_t stream)
{
    const float* node_states = (const float*)d_in[0];
    const int*   edges       = (const int*)d_in[1];
    const float* w_qkv = (const float*)d_in[2];
    const float* b_qkv = (const float*)d_in[3];
    const float* w_out = (const float*)d_in[4];
    const float* b_out = (const float*)d_in[5];
    const float* w1    = (const float*)d_in[6];
    const float* b1    = (const float*)d_in[7];
    const float* w2    = (const float*)d_in[8];
    const float* b2    = (const float*)d_in[9];
    const float* g1    = (const float*)d_in[10];
    const float* beta1 = (const float*)d_in[11];
    const float* g2    = (const float*)d_in[12];
    const float* beta2 = (const float*)d_in[13];

    const int N  = in_sizes[0] / D_DIM;      // 40000
    const int M  = in_sizes[1] / 2;          // 640000
    const int MP = ((N + 127) / 128) * 128;  // 40064
    const int* e_src = edges;
    const int* e_tgt = edges + M;

    float* out_new = (float*)d_out;
    float* out_old = (float*)d_out + (size_t)N * D_DIM;

    size_t off = 0;
    auto alloc = [&](size_t bytes) -> void* {
        void* p = (char*)d_ws + off;
        off += (bytes + 255) & ~(size_t)255;
        return p;
    };
    short* ns_bf   = (short*)alloc((size_t)MP * D_DIM * 2);
    // region: qkv_bf [MP][384] early; xbuf f32 [MP][128] + xbuf_bf [MP][128] later
    char*  region  = (char*)alloc((size_t)MP * 384 * 2);
    short* qkv_bf  = (short*)region;
    float* xbuf    = (float*)region;
    short* xbuf_bf = (short*)(region + (size_t)MP * D_DIM * 4);
    short* agg_bf  = (short*)alloc((size_t)MP * D_DIM * 2);
    float* msg     = (float*)alloc((size_t)MP * D_DIM * 4);     // also ff2 out
    short* ff1_bf  = (short*)alloc((size_t)MP * FF_DIM * 2);
    short* wqkv_bf = (short*)alloc((size_t)384 * 128 * 2);
    short* wout_bf = (short*)alloc((size_t)128 * 128 * 2);
    short* w1_bf   = (short*)alloc((size_t)512 * 128 * 2);
    short* w2_bf   = (short*)alloc((size_t)128 * 512 * 2);
    int* counts    = (int*)alloc((size_t)N * 4);
    int* offsets   = (int*)alloc((size_t)(N + 1) * 4);
    int* cursor    = (int*)alloc((size_t)N * 4);
    int* bsum      = (int*)alloc((size_t)256 * 4);
    int* csr_src   = (int*)alloc((size_t)M * 4);
    (void)ws_size;

    const int nb = (N + 255) / 256;   // 157 scan blocks

    // conversions (+ old-state copy fused)
    conv_ns_kernel<<<(MP * D_DIM / 4 + 255) / 256, 256, 0, stream>>>(
        node_states, ns_bf, out_old, N * D_DIM, MP * D_DIM);
    conv_w_kernel<<<(512 * 128 + 255) / 256, 256, 0, stream>>>(
        w_qkv, w_out, w1, w2, wqkv_bf, wout_bf, w1_bf, w2_bf,
        384 * 128, 128 * 128, 512 * 128, 128 * 512);

    // CSR build
    hipMemsetAsync(counts, 0, (size_t)N * 4, stream);
    count_kernel<<<(M + 255) / 256, 256, 0, stream>>>(e_tgt, counts, M);
    scan1_kernel<<<nb, 256, 0, stream>>>(counts, offsets, bsum, N);
    scan2_kernel<<<1, 256, 0, stream>>>(bsum, nb);
    scan3_kernel<<<nb, 256, 0, stream>>>(offsets, bsum, cursor, N, M);
    scatter_kernel<<<(M + 255) / 256, 256, 0, stream>>>(e_src, e_tgt, cursor,
                                                        csr_src, M);

    // 1) qkv = ns @ w_qkv^T + b_qkv  (bf16 out, KV-interleaved)
    {
        dim3 grid(384 / 128, MP / 128);
        gemm_mfma<1, 0, 1><<<grid, 256, 0, stream>>>(ns_bf, wqkv_bf, b_qkv,
                                                     qkv_bf, 384, 128);
    }
    // 2) attention aggregation
    attn_kernel<<<MP / 4, 256, 0, stream>>>(qkv_bf, offsets, csr_src,
                                            agg_bf, N, MP);
    // 3) msg = agg @ w_out^T + b_out  (f32 out)
    {
        dim3 grid(1, MP / 128);
        gemm_mfma<0, 0, 0><<<grid, 256, 0, stream>>>(agg_bf, wout_bf, b_out,
                                                     msg, 128, 128);
    }
    // 4) x = LN(ns + msg)  -> xbuf f32 + xbuf_bf   (overwrites dead qkv_bf)
    ln1_kernel<<<MP / 4, 256, 0, stream>>>(node_states, msg, g1, beta1,
                                           xbuf, xbuf_bf, N, MP);
    // 5) ff1 = relu(x @ w1^T + b1)  (bf16 out)
    {
        dim3 grid(FF_DIM / 128, MP / 128);
        gemm_mfma<1, 1, 0><<<grid, 256, 0, stream>>>(xbuf_bf, w1_bf, b1,
                                                     ff1_bf, FF_DIM, 128);
    }
    // 6) ff2 = ff1 @ w2^T + b2  (f32 out, reuse msg)
    {
        dim3 grid(1, MP / 128);
        gemm_mfma<0, 0, 0><<<grid, 256, 0, stream>>>(ff1_bf, w2_bf, b2,
                                                     msg, 128, 512);
    }
    // 7) out = LN(x + ff2)
    ln2_kernel<<<(N + 3) / 4, 256, 0, stream>>>(xbuf, msg, g2, beta2,
                                                out_new, N);
}